// Round 1
// baseline (825.535 us; speedup 1.0000x reference)
//
#include <hip/hip_runtime.h>

#define N_NODES 50000
#define N_EDGES 800000
#define N_GRAPHS 128
#define IN_DIM 256
#define OUT_DIM 128
#define NEG_SLOPE 0.01f

#define BM 64
#define BK 32
#define RCHUNK 64

// ---------------- degree histograms ----------------
__global__ __launch_bounds__(256) void deg_kernel(const int* __restrict__ src,
                                                  const int* __restrict__ dst,
                                                  int* __restrict__ deg_out,
                                                  int* __restrict__ deg_in) {
    int e = blockIdx.x * 256 + threadIdx.x;
    if (e < N_EDGES) {
        atomicAdd(&deg_out[src[e]], 1);
        atomicAdd(&deg_in[dst[e]], 1);
    }
}

__global__ __launch_bounds__(256) void norm_kernel(const int* __restrict__ deg_out,
                                                   const int* __restrict__ deg_in,
                                                   float* __restrict__ out_norm,
                                                   float* __restrict__ in_norm) {
    int i = blockIdx.x * 256 + threadIdx.x;
    if (i < N_NODES) {
        int dо = deg_out[i] > 1 ? deg_out[i] : 1;
        int di = deg_in[i] > 1 ? deg_in[i] : 1;
        out_norm[i] = rsqrtf((float)dо);
        in_norm[i]  = rsqrtf((float)di);
    }
}

// ---------------- fold Wc = w_red @ w2, bc = b_red @ w2 ----------------
__global__ __launch_bounds__(128) void wc_kernel(const float* __restrict__ w_red,
                                                 const float* __restrict__ b_red,
                                                 const float* __restrict__ w2,
                                                 float* __restrict__ Wc,
                                                 float* __restrict__ bc) {
    int j = threadIdx.x;   // 0..127
    int i = blockIdx.x;    // 0..256 (block 256 computes bc)
    const float* vin = (i < IN_DIM) ? (w_red + (size_t)i * OUT_DIM) : b_red;
    float s = 0.f;
    for (int k = 0; k < OUT_DIM; ++k) s = fmaf(vin[k], w2[k * OUT_DIM + j], s);
    if (i < IN_DIM) Wc[i * OUT_DIM + j] = s;
    else            bc[j] = s;
}

// ---------------- z = out_norm * (feat @ Wc + bc) ----------------
// BM=64 rows, BN=128 (full width), BK=32. 256 threads, 4x8 micro-tile.
__global__ __launch_bounds__(256) void gemm_z(const float* __restrict__ feat,
                                              const float* __restrict__ Wc,
                                              const float* __restrict__ bc,
                                              const float* __restrict__ out_norm,
                                              float* __restrict__ z) {
    __shared__ float As[BM][BK + 4];     // row-major A tile, padded for f4 align
    __shared__ float Bs[BK][OUT_DIM];    // k-major B tile

    int t  = threadIdx.x;
    int bm = blockIdx.x * BM;
    int cg = t & 15;   // col group: cols cg*8 .. cg*8+7
    int rg = t >> 4;   // row group: rows rg*4 .. rg*4+3

    float acc[4][8];
#pragma unroll
    for (int i = 0; i < 4; ++i)
#pragma unroll
        for (int j = 0; j < 8; ++j) acc[i][j] = 0.f;

    for (int k0 = 0; k0 < IN_DIM; k0 += BK) {
        // load A tile: 64 rows x 32 k, float4 per thread x2
        int ar = t >> 3;          // 0..31
        int ak = (t & 7) * 4;     // 0..28
#pragma unroll
        for (int h = 0; h < 2; ++h) {
            int row = ar + h * 32;
            int gm  = bm + row;
            float4 v = make_float4(0.f, 0.f, 0.f, 0.f);
            if (gm < N_NODES) v = *(const float4*)&feat[(size_t)gm * IN_DIM + k0 + ak];
            *(float4*)&As[row][ak] = v;
        }
        // load B tile: 32 k x 128 n
        int bn  = (t & 31) * 4;   // 0..124
        int bk0 = t >> 5;         // 0..7
#pragma unroll
        for (int i = 0; i < 4; ++i) {
            int k = bk0 + i * 8;
            *(float4*)&Bs[k][bn] = *(const float4*)&Wc[(size_t)(k0 + k) * OUT_DIM + bn];
        }
        __syncthreads();

#pragma unroll
        for (int k = 0; k < BK; ++k) {
            float a[4];
#pragma unroll
            for (int i = 0; i < 4; ++i) a[i] = As[rg * 4 + i][k];
            float4 b0 = *(const float4*)&Bs[k][cg * 8];
            float4 b1 = *(const float4*)&Bs[k][cg * 8 + 4];
            float b[8] = {b0.x, b0.y, b0.z, b0.w, b1.x, b1.y, b1.z, b1.w};
#pragma unroll
            for (int i = 0; i < 4; ++i)
#pragma unroll
                for (int j = 0; j < 8; ++j)
                    acc[i][j] = fmaf(a[i], b[j], acc[i][j]);
        }
        __syncthreads();
    }

    // epilogue: z = out_norm * (acc + bc)
#pragma unroll
    for (int i = 0; i < 4; ++i) {
        int gm = bm + rg * 4 + i;
        if (gm < N_NODES) {
            float on = out_norm[gm];
            float4 o0, o1;
            o0.x = on * (acc[i][0] + bc[cg * 8 + 0]);
            o0.y = on * (acc[i][1] + bc[cg * 8 + 1]);
            o0.z = on * (acc[i][2] + bc[cg * 8 + 2]);
            o0.w = on * (acc[i][3] + bc[cg * 8 + 3]);
            o1.x = on * (acc[i][4] + bc[cg * 8 + 4]);
            o1.y = on * (acc[i][5] + bc[cg * 8 + 5]);
            o1.z = on * (acc[i][6] + bc[cg * 8 + 6]);
            o1.w = on * (acc[i][7] + bc[cg * 8 + 7]);
            *(float4*)&z[(size_t)gm * OUT_DIM + cg * 8]     = o0;
            *(float4*)&z[(size_t)gm * OUT_DIM + cg * 8 + 4] = o1;
        }
    }
}

// ---------------- scatter: agg[dst] += z[src], one wave per edge ----------------
__global__ __launch_bounds__(256) void scatter_kernel(const float* __restrict__ z,
                                                      const int* __restrict__ src,
                                                      const int* __restrict__ dst,
                                                      float* __restrict__ agg) {
    int wid  = blockIdx.x * 4 + (threadIdx.x >> 6);  // global wave = edge id
    int lane = threadIdx.x & 63;
    if (wid >= N_EDGES) return;
    int s = src[wid];
    int d = dst[wid];
    float2 v = *(const float2*)&z[(size_t)s * OUT_DIM + lane * 2];
    atomicAdd(&agg[(size_t)d * OUT_DIM + lane * 2 + 0], v.x);
    atomicAdd(&agg[(size_t)d * OUT_DIM + lane * 2 + 1], v.y);
}

// ---------------- fused leaky_relu + per-graph readout (graph_ids sorted) ----------------
__global__ __launch_bounds__(128) void readout_kernel(const float* __restrict__ agg,
                                                      const float* __restrict__ in_norm,
                                                      const int* __restrict__ gids,
                                                      const float* __restrict__ b2,
                                                      float* __restrict__ g) {
    int j    = threadIdx.x;           // column 0..127
    int n0   = blockIdx.x * RCHUNK;
    int nend = n0 + RCHUNK;
    if (nend > N_NODES) nend = N_NODES;
    float bj  = b2[j];
    float acc = 0.f;
    int   cur = gids[n0];
    for (int n = n0; n < nend; ++n) {
        int gid = gids[n];
        if (gid != cur) {
            atomicAdd(&g[cur * OUT_DIM + j], acc);
            acc = 0.f;
            cur = gid;
        }
        float h = in_norm[n] * agg[(size_t)n * OUT_DIM + j] + bj;
        acc += (h > 0.f) ? h : NEG_SLOPE * h;
    }
    atomicAdd(&g[cur * OUT_DIM + j], acc);
}

// ---------------- classifier: out = g @ w_cls + b_cls ----------------
__global__ __launch_bounds__(256) void cls_kernel(const float* __restrict__ g,
                                                  const float* __restrict__ w_cls,
                                                  const float* __restrict__ b_cls,
                                                  float* __restrict__ out) {
    int t  = threadIdx.x;    // 0..255
    int gr = t >> 1;
    int c  = t & 1;
    float s = b_cls[c];
    for (int k = 0; k < OUT_DIM; ++k) s = fmaf(g[gr * OUT_DIM + k], w_cls[k * 2 + c], s);
    out[t] = s;   // out[gr*2 + c]
}

extern "C" void kernel_launch(void* const* d_in, const int* in_sizes, int n_in,
                              void* d_out, int out_size, void* d_ws, size_t ws_size,
                              hipStream_t stream) {
    const float* feat  = (const float*)d_in[0];
    const int*   src   = (const int*)d_in[1];
    const int*   dst   = (const int*)d_in[2];
    const int*   gids  = (const int*)d_in[3];
    const float* w_red = (const float*)d_in[4];
    const float* b_red = (const float*)d_in[5];
    const float* w_gcn = (const float*)d_in[6];
    const float* b_gcn = (const float*)d_in[7];
    const float* w_cls = (const float*)d_in[8];
    const float* b_cls = (const float*)d_in[9];
    float* out = (float*)d_out;

    // workspace layout
    float* z        = (float*)d_ws;                       // 6.4M floats
    float* agg      = z + (size_t)N_NODES * OUT_DIM;      // 6.4M floats
    float* out_norm = agg + (size_t)N_NODES * OUT_DIM;    // 50000
    float* in_norm  = out_norm + N_NODES;                 // 50000
    int*   deg_out  = (int*)(in_norm + N_NODES);          // 50000
    int*   deg_in   = deg_out + N_NODES;                  // 50000
    float* Wc       = (float*)(deg_in + N_NODES);         // 32768
    float* bc       = Wc + IN_DIM * OUT_DIM;              // 128
    float* g        = bc + OUT_DIM;                       // 16384

    const float* w2 = w_gcn + 2 * OUT_DIM * OUT_DIM;      // layer 2 weights
    const float* b2 = b_gcn + 2 * OUT_DIM;                // layer 2 bias

    hipMemsetAsync(agg, 0, (size_t)N_NODES * OUT_DIM * sizeof(float), stream);
    hipMemsetAsync(deg_out, 0, 2 * (size_t)N_NODES * sizeof(int), stream);
    hipMemsetAsync(g, 0, (size_t)N_GRAPHS * OUT_DIM * sizeof(float), stream);

    deg_kernel<<<(N_EDGES + 255) / 256, 256, 0, stream>>>(src, dst, deg_out, deg_in);
    norm_kernel<<<(N_NODES + 255) / 256, 256, 0, stream>>>(deg_out, deg_in, out_norm, in_norm);
    wc_kernel<<<IN_DIM + 1, OUT_DIM, 0, stream>>>(w_red, b_red, w2, Wc, bc);
    gemm_z<<<(N_NODES + BM - 1) / BM, 256, 0, stream>>>(feat, Wc, bc, out_norm, z);
    scatter_kernel<<<(N_EDGES + 3) / 4, 256, 0, stream>>>(z, src, dst, agg);
    readout_kernel<<<(N_NODES + RCHUNK - 1) / RCHUNK, 128, 0, stream>>>(agg, in_norm, gids, b2, g);
    cls_kernel<<<1, 256, 0, stream>>>(g, w_cls, b_cls, out);
}

// Round 2
// 394.067 us; speedup vs baseline: 2.0949x; 2.0949x over previous
//
#include <hip/hip_runtime.h>

#define N_NODES 50000
#define N_EDGES 800000
#define N_GRAPHS 128
#define IN_DIM 256
#define OUT_DIM 128
#define NEG_SLOPE 0.01f

#define BM 64
#define BK 32
#define RCHUNK 64

// ---------------- degree histograms ----------------
__global__ __launch_bounds__(256) void deg_kernel(const int* __restrict__ src,
                                                  const int* __restrict__ dst,
                                                  int* __restrict__ deg_out,
                                                  int* __restrict__ deg_in) {
    int e = blockIdx.x * 256 + threadIdx.x;
    if (e < N_EDGES) {
        atomicAdd(&deg_out[src[e]], 1);
        atomicAdd(&deg_in[dst[e]], 1);
    }
}

__global__ __launch_bounds__(256) void norm_kernel(const int* __restrict__ deg_out,
                                                   const int* __restrict__ deg_in,
                                                   float* __restrict__ out_norm,
                                                   float* __restrict__ in_norm) {
    int i = blockIdx.x * 256 + threadIdx.x;
    if (i < N_NODES) {
        int dq = deg_out[i] > 1 ? deg_out[i] : 1;
        int di = deg_in[i] > 1 ? deg_in[i] : 1;
        out_norm[i] = rsqrtf((float)dq);
        in_norm[i]  = rsqrtf((float)di);
    }
}

// ---------------- exclusive scan of deg_in -> row_ofs, cursor (single block) ----------------
__global__ __launch_bounds__(1024) void scan_kernel(const int* __restrict__ deg_in,
                                                    int* __restrict__ row_ofs,
                                                    int* __restrict__ cursor) {
    __shared__ int part[1024];
    int t = threadIdx.x;
    const int CH = (N_NODES + 1023) / 1024;  // 49
    int base = t * CH;
    int s = 0;
    for (int i = 0; i < CH; ++i) {
        int idx = base + i;
        if (idx < N_NODES) s += deg_in[idx];
    }
    part[t] = s;
    __syncthreads();
    // Hillis-Steele inclusive scan over 1024 partials
    for (int off = 1; off < 1024; off <<= 1) {
        int v = part[t];
        int u = (t >= off) ? part[t - off] : 0;
        __syncthreads();
        part[t] = v + u;
        __syncthreads();
    }
    int run = (t == 0) ? 0 : part[t - 1];
    for (int i = 0; i < CH; ++i) {
        int idx = base + i;
        if (idx < N_NODES) {
            row_ofs[idx] = run;
            cursor[idx]  = run;
            run += deg_in[idx];
        }
    }
    if (t == 1023) row_ofs[N_NODES] = run;  // chunks 0..1022 already cover all nodes
}

// ---------------- bucket fill: esrc grouped by dst ----------------
__global__ __launch_bounds__(256) void build_kernel(const int* __restrict__ src,
                                                    const int* __restrict__ dst,
                                                    int* __restrict__ cursor,
                                                    int* __restrict__ esrc) {
    int e = blockIdx.x * 256 + threadIdx.x;
    if (e < N_EDGES) {
        int pos = atomicAdd(&cursor[dst[e]], 1);
        esrc[pos] = src[e];
    }
}

// ---------------- fold Wc = w_red @ w2, bc = b_red @ w2 ----------------
__global__ __launch_bounds__(128) void wc_kernel(const float* __restrict__ w_red,
                                                 const float* __restrict__ b_red,
                                                 const float* __restrict__ w2,
                                                 float* __restrict__ Wc,
                                                 float* __restrict__ bc) {
    int j = threadIdx.x;   // 0..127
    int i = blockIdx.x;    // 0..256 (block 256 computes bc)
    const float* vin = (i < IN_DIM) ? (w_red + (size_t)i * OUT_DIM) : b_red;
    float s = 0.f;
    for (int k = 0; k < OUT_DIM; ++k) s = fmaf(vin[k], w2[k * OUT_DIM + j], s);
    if (i < IN_DIM) Wc[i * OUT_DIM + j] = s;
    else            bc[j] = s;
}

// ---------------- z = out_norm * (feat @ Wc + bc) ----------------
__global__ __launch_bounds__(256) void gemm_z(const float* __restrict__ feat,
                                              const float* __restrict__ Wc,
                                              const float* __restrict__ bc,
                                              const float* __restrict__ out_norm,
                                              float* __restrict__ z) {
    __shared__ float As[BM][BK + 4];
    __shared__ float Bs[BK][OUT_DIM];

    int t  = threadIdx.x;
    int bm = blockIdx.x * BM;
    int cg = t & 15;   // col group: cols cg*8 .. cg*8+7
    int rg = t >> 4;   // row group: rows rg*4 .. rg*4+3

    float acc[4][8];
#pragma unroll
    for (int i = 0; i < 4; ++i)
#pragma unroll
        for (int j = 0; j < 8; ++j) acc[i][j] = 0.f;

    for (int k0 = 0; k0 < IN_DIM; k0 += BK) {
        int ar = t >> 3;
        int ak = (t & 7) * 4;
#pragma unroll
        for (int h = 0; h < 2; ++h) {
            int row = ar + h * 32;
            int gm  = bm + row;
            float4 v = make_float4(0.f, 0.f, 0.f, 0.f);
            if (gm < N_NODES) v = *(const float4*)&feat[(size_t)gm * IN_DIM + k0 + ak];
            *(float4*)&As[row][ak] = v;
        }
        int bn  = (t & 31) * 4;
        int bk0 = t >> 5;
#pragma unroll
        for (int i = 0; i < 4; ++i) {
            int k = bk0 + i * 8;
            *(float4*)&Bs[k][bn] = *(const float4*)&Wc[(size_t)(k0 + k) * OUT_DIM + bn];
        }
        __syncthreads();

#pragma unroll
        for (int k = 0; k < BK; ++k) {
            float a[4];
#pragma unroll
            for (int i = 0; i < 4; ++i) a[i] = As[rg * 4 + i][k];
            float4 b0 = *(const float4*)&Bs[k][cg * 8];
            float4 b1 = *(const float4*)&Bs[k][cg * 8 + 4];
            float b[8] = {b0.x, b0.y, b0.z, b0.w, b1.x, b1.y, b1.z, b1.w};
#pragma unroll
            for (int i = 0; i < 4; ++i)
#pragma unroll
                for (int j = 0; j < 8; ++j)
                    acc[i][j] = fmaf(a[i], b[j], acc[i][j]);
        }
        __syncthreads();
    }

#pragma unroll
    for (int i = 0; i < 4; ++i) {
        int gm = bm + rg * 4 + i;
        if (gm < N_NODES) {
            float on = out_norm[gm];
            float4 o0, o1;
            o0.x = on * (acc[i][0] + bc[cg * 8 + 0]);
            o0.y = on * (acc[i][1] + bc[cg * 8 + 1]);
            o0.z = on * (acc[i][2] + bc[cg * 8 + 2]);
            o0.w = on * (acc[i][3] + bc[cg * 8 + 3]);
            o1.x = on * (acc[i][4] + bc[cg * 8 + 4]);
            o1.y = on * (acc[i][5] + bc[cg * 8 + 5]);
            o1.z = on * (acc[i][6] + bc[cg * 8 + 6]);
            o1.w = on * (acc[i][7] + bc[cg * 8 + 7]);
            *(float4*)&z[(size_t)gm * OUT_DIM + cg * 8]     = o0;
            *(float4*)&z[(size_t)gm * OUT_DIM + cg * 8 + 4] = o1;
        }
    }
}

// ---------------- pull-model aggregate + fused in_norm/bias/leaky_relu ----------------
// one 128-thread block per destination node; h = lrelu(in_norm*sum(z[src]) + b2)
__global__ __launch_bounds__(128) void gather_kernel(const float* __restrict__ z,
                                                     const int* __restrict__ esrc,
                                                     const int* __restrict__ row_ofs,
                                                     const float* __restrict__ in_norm,
                                                     const float* __restrict__ b2,
                                                     float* __restrict__ h) {
    int n = blockIdx.x;
    int j = threadIdx.x;
    int e0 = row_ofs[n];
    int e1 = row_ofs[n + 1];
    float acc = 0.f;
    int e = e0;
    for (; e + 4 <= e1; e += 4) {
        int sa = esrc[e + 0];
        int sb = esrc[e + 1];
        int sc = esrc[e + 2];
        int sd = esrc[e + 3];
        float va = z[(size_t)sa * OUT_DIM + j];
        float vb = z[(size_t)sb * OUT_DIM + j];
        float vc = z[(size_t)sc * OUT_DIM + j];
        float vd = z[(size_t)sd * OUT_DIM + j];
        acc += (va + vb) + (vc + vd);
    }
    for (; e < e1; ++e) acc += z[(size_t)esrc[e] * OUT_DIM + j];
    float hv = in_norm[n] * acc + b2[j];
    h[(size_t)n * OUT_DIM + j] = (hv > 0.f) ? hv : NEG_SLOPE * hv;
}

// ---------------- per-graph readout (graph_ids sorted) ----------------
__global__ __launch_bounds__(128) void readout_kernel(const float* __restrict__ h,
                                                      const int* __restrict__ gids,
                                                      float* __restrict__ g) {
    int j    = threadIdx.x;
    int n0   = blockIdx.x * RCHUNK;
    int nend = n0 + RCHUNK;
    if (nend > N_NODES) nend = N_NODES;
    float acc = 0.f;
    int   cur = gids[n0];
    for (int n = n0; n < nend; ++n) {
        int gid = gids[n];
        if (gid != cur) {
            atomicAdd(&g[cur * OUT_DIM + j], acc);
            acc = 0.f;
            cur = gid;
        }
        acc += h[(size_t)n * OUT_DIM + j];
    }
    atomicAdd(&g[cur * OUT_DIM + j], acc);
}

// ---------------- classifier: out = g @ w_cls + b_cls ----------------
__global__ __launch_bounds__(256) void cls_kernel(const float* __restrict__ g,
                                                  const float* __restrict__ w_cls,
                                                  const float* __restrict__ b_cls,
                                                  float* __restrict__ out) {
    int t  = threadIdx.x;
    int gr = t >> 1;
    int c  = t & 1;
    float s = b_cls[c];
    for (int k = 0; k < OUT_DIM; ++k) s = fmaf(g[gr * OUT_DIM + k], w_cls[k * 2 + c], s);
    out[t] = s;
}

extern "C" void kernel_launch(void* const* d_in, const int* in_sizes, int n_in,
                              void* d_out, int out_size, void* d_ws, size_t ws_size,
                              hipStream_t stream) {
    const float* feat  = (const float*)d_in[0];
    const int*   src   = (const int*)d_in[1];
    const int*   dst   = (const int*)d_in[2];
    const int*   gids  = (const int*)d_in[3];
    const float* w_red = (const float*)d_in[4];
    const float* b_red = (const float*)d_in[5];
    const float* w_gcn = (const float*)d_in[6];
    const float* b_gcn = (const float*)d_in[7];
    const float* w_cls = (const float*)d_in[8];
    const float* b_cls = (const float*)d_in[9];
    float* out = (float*)d_out;

    // workspace layout
    float* z        = (float*)d_ws;                       // 6.4M floats
    float* h        = z + (size_t)N_NODES * OUT_DIM;      // 6.4M floats
    float* out_norm = h + (size_t)N_NODES * OUT_DIM;      // 50000
    float* in_norm  = out_norm + N_NODES;                 // 50000
    int*   deg_out  = (int*)(in_norm + N_NODES);          // 50000
    int*   deg_in   = deg_out + N_NODES;                  // 50000
    int*   row_ofs  = deg_in + N_NODES;                   // 50001
    int*   cursor   = row_ofs + N_NODES + 1;              // 50000
    int*   esrc     = cursor + N_NODES;                   // 800000
    float* Wc       = (float*)(esrc + N_EDGES);           // 32768
    float* bc       = Wc + IN_DIM * OUT_DIM;              // 128
    float* g        = bc + OUT_DIM;                       // 16384

    const float* w2 = w_gcn + 2 * OUT_DIM * OUT_DIM;      // layer 2 weights
    const float* b2 = b_gcn + 2 * OUT_DIM;                // layer 2 bias

    hipMemsetAsync(deg_out, 0, 2 * (size_t)N_NODES * sizeof(int), stream);
    hipMemsetAsync(g, 0, (size_t)N_GRAPHS * OUT_DIM * sizeof(float), stream);

    deg_kernel<<<(N_EDGES + 255) / 256, 256, 0, stream>>>(src, dst, deg_out, deg_in);
    norm_kernel<<<(N_NODES + 255) / 256, 256, 0, stream>>>(deg_out, deg_in, out_norm, in_norm);
    scan_kernel<<<1, 1024, 0, stream>>>(deg_in, row_ofs, cursor);
    build_kernel<<<(N_EDGES + 255) / 256, 256, 0, stream>>>(src, dst, cursor, esrc);
    wc_kernel<<<IN_DIM + 1, OUT_DIM, 0, stream>>>(w_red, b_red, w2, Wc, bc);
    gemm_z<<<(N_NODES + BM - 1) / BM, 256, 0, stream>>>(feat, Wc, bc, out_norm, z);
    gather_kernel<<<N_NODES, 128, 0, stream>>>(z, esrc, row_ofs, in_norm, b2, h);
    readout_kernel<<<(N_NODES + RCHUNK - 1) / RCHUNK, 128, 0, stream>>>(h, gids, g);
    cls_kernel<<<1, 256, 0, stream>>>(g, w_cls, b_cls, out);
}

// Round 3
// 282.034 us; speedup vs baseline: 2.9271x; 1.3972x over previous
//
#include <hip/hip_runtime.h>

#define N_NODES 50000
#define N_EDGES 800000
#define N_GRAPHS 128
#define IN_DIM 256
#define OUT_DIM 128
#define NEG_SLOPE 0.01f

#define BM 64
#define BK 32
#define RCHUNK 64
#define NB_SCAN ((N_NODES + 255) / 256)   // 196 blocks for the scan

// ---------------- degree histograms ----------------
__global__ __launch_bounds__(256) void deg_kernel(const int* __restrict__ src,
                                                  const int* __restrict__ dst,
                                                  int* __restrict__ deg_out,
                                                  int* __restrict__ deg_in) {
    int e = blockIdx.x * 256 + threadIdx.x;
    if (e < N_EDGES) {
        atomicAdd(&deg_out[src[e]], 1);
        atomicAdd(&deg_in[dst[e]], 1);
    }
}

__global__ __launch_bounds__(256) void norm_kernel(const int* __restrict__ deg_out,
                                                   const int* __restrict__ deg_in,
                                                   float* __restrict__ out_norm,
                                                   float* __restrict__ in_norm) {
    int i = blockIdx.x * 256 + threadIdx.x;
    if (i < N_NODES) {
        int dq = deg_out[i] > 1 ? deg_out[i] : 1;
        int di = deg_in[i] > 1 ? deg_in[i] : 1;
        out_norm[i] = rsqrtf((float)dq);
        in_norm[i]  = rsqrtf((float)di);
    }
}

// ---------------- multi-block scan phase 1: per-block sums ----------------
__global__ __launch_bounds__(256) void partial_kernel(const int* __restrict__ deg_in,
                                                      int* __restrict__ bsum) {
    __shared__ int red[256];
    int t   = threadIdx.x;
    int idx = blockIdx.x * 256 + t;
    red[t] = (idx < N_NODES) ? deg_in[idx] : 0;
    __syncthreads();
    for (int off = 128; off > 0; off >>= 1) {
        if (t < off) red[t] += red[t + off];
        __syncthreads();
    }
    if (t == 0) bsum[blockIdx.x] = red[0];
}

// ---------------- phase 2: scan the 196 block sums (one block) ----------------
__global__ __launch_bounds__(256) void scan_bsums(const int* __restrict__ bsum,
                                                  int* __restrict__ bofs,
                                                  int* __restrict__ row_ofs) {
    __shared__ int sh[256];
    int t = threadIdx.x;
    int v = (t < NB_SCAN) ? bsum[t] : 0;
    sh[t] = v;
    __syncthreads();
    for (int off = 1; off < 256; off <<= 1) {
        int a = sh[t];
        int b = (t >= off) ? sh[t - off] : 0;
        __syncthreads();
        sh[t] = a + b;
        __syncthreads();
    }
    if (t < NB_SCAN) bofs[t] = sh[t] - v;                    // exclusive
    if (t == 255)    row_ofs[N_NODES] = sh[NB_SCAN - 1];     // total (= N_EDGES)
}

// ---------------- phase 3: block-local scan + offset -> row_ofs, cursor ----------------
__global__ __launch_bounds__(256) void fill_kernel(const int* __restrict__ deg_in,
                                                   const int* __restrict__ bofs,
                                                   int* __restrict__ row_ofs,
                                                   int* __restrict__ cursor) {
    __shared__ int sh[256];
    int t   = threadIdx.x;
    int idx = blockIdx.x * 256 + t;
    int v   = (idx < N_NODES) ? deg_in[idx] : 0;
    sh[t] = v;
    __syncthreads();
    for (int off = 1; off < 256; off <<= 1) {
        int a = sh[t];
        int b = (t >= off) ? sh[t - off] : 0;
        __syncthreads();
        sh[t] = a + b;
        __syncthreads();
    }
    if (idx < N_NODES) {
        int r = bofs[blockIdx.x] + sh[t] - v;   // global exclusive prefix
        row_ofs[idx] = r;
        cursor[idx]  = r;
    }
}

// ---------------- bucket fill: esrc grouped by dst ----------------
__global__ __launch_bounds__(256) void build_kernel(const int* __restrict__ src,
                                                    const int* __restrict__ dst,
                                                    int* __restrict__ cursor,
                                                    int* __restrict__ esrc) {
    int e = blockIdx.x * 256 + threadIdx.x;
    if (e < N_EDGES) {
        int pos = atomicAdd(&cursor[dst[e]], 1);
        esrc[pos] = src[e];
    }
}

// ---------------- fold Wc = w_red @ w2, bc = b_red @ w2 ----------------
__global__ __launch_bounds__(128) void wc_kernel(const float* __restrict__ w_red,
                                                 const float* __restrict__ b_red,
                                                 const float* __restrict__ w2,
                                                 float* __restrict__ Wc,
                                                 float* __restrict__ bc) {
    int j = threadIdx.x;   // 0..127
    int i = blockIdx.x;    // 0..256 (block 256 computes bc)
    const float* vin = (i < IN_DIM) ? (w_red + (size_t)i * OUT_DIM) : b_red;
    float s = 0.f;
    for (int k = 0; k < OUT_DIM; ++k) s = fmaf(vin[k], w2[k * OUT_DIM + j], s);
    if (i < IN_DIM) Wc[i * OUT_DIM + j] = s;
    else            bc[j] = s;
}

// ---------------- z = out_norm * (feat @ Wc + bc) ----------------
__global__ __launch_bounds__(256) void gemm_z(const float* __restrict__ feat,
                                              const float* __restrict__ Wc,
                                              const float* __restrict__ bc,
                                              const float* __restrict__ out_norm,
                                              float* __restrict__ z) {
    __shared__ float As[BM][BK + 4];
    __shared__ float Bs[BK][OUT_DIM];

    int t  = threadIdx.x;
    int bm = blockIdx.x * BM;
    int cg = t & 15;
    int rg = t >> 4;

    float acc[4][8];
#pragma unroll
    for (int i = 0; i < 4; ++i)
#pragma unroll
        for (int j = 0; j < 8; ++j) acc[i][j] = 0.f;

    for (int k0 = 0; k0 < IN_DIM; k0 += BK) {
        int ar = t >> 3;
        int ak = (t & 7) * 4;
#pragma unroll
        for (int h = 0; h < 2; ++h) {
            int row = ar + h * 32;
            int gm  = bm + row;
            float4 v = make_float4(0.f, 0.f, 0.f, 0.f);
            if (gm < N_NODES) v = *(const float4*)&feat[(size_t)gm * IN_DIM + k0 + ak];
            *(float4*)&As[row][ak] = v;
        }
        int bn  = (t & 31) * 4;
        int bk0 = t >> 5;
#pragma unroll
        for (int i = 0; i < 4; ++i) {
            int k = bk0 + i * 8;
            *(float4*)&Bs[k][bn] = *(const float4*)&Wc[(size_t)(k0 + k) * OUT_DIM + bn];
        }
        __syncthreads();

#pragma unroll
        for (int k = 0; k < BK; ++k) {
            float a[4];
#pragma unroll
            for (int i = 0; i < 4; ++i) a[i] = As[rg * 4 + i][k];
            float4 b0 = *(const float4*)&Bs[k][cg * 8];
            float4 b1 = *(const float4*)&Bs[k][cg * 8 + 4];
            float b[8] = {b0.x, b0.y, b0.z, b0.w, b1.x, b1.y, b1.z, b1.w};
#pragma unroll
            for (int i = 0; i < 4; ++i)
#pragma unroll
                for (int j = 0; j < 8; ++j)
                    acc[i][j] = fmaf(a[i], b[j], acc[i][j]);
        }
        __syncthreads();
    }

#pragma unroll
    for (int i = 0; i < 4; ++i) {
        int gm = bm + rg * 4 + i;
        if (gm < N_NODES) {
            float on = out_norm[gm];
            float4 o0, o1;
            o0.x = on * (acc[i][0] + bc[cg * 8 + 0]);
            o0.y = on * (acc[i][1] + bc[cg * 8 + 1]);
            o0.z = on * (acc[i][2] + bc[cg * 8 + 2]);
            o0.w = on * (acc[i][3] + bc[cg * 8 + 3]);
            o1.x = on * (acc[i][4] + bc[cg * 8 + 4]);
            o1.y = on * (acc[i][5] + bc[cg * 8 + 5]);
            o1.z = on * (acc[i][6] + bc[cg * 8 + 6]);
            o1.w = on * (acc[i][7] + bc[cg * 8 + 7]);
            *(float4*)&z[(size_t)gm * OUT_DIM + cg * 8]     = o0;
            *(float4*)&z[(size_t)gm * OUT_DIM + cg * 8 + 4] = o1;
        }
    }
}

// ---------------- pull-model aggregate + fused in_norm/bias/leaky_relu ----------------
__global__ __launch_bounds__(128) void gather_kernel(const float* __restrict__ z,
                                                     const int* __restrict__ esrc,
                                                     const int* __restrict__ row_ofs,
                                                     const float* __restrict__ in_norm,
                                                     const float* __restrict__ b2,
                                                     float* __restrict__ h) {
    int n = blockIdx.x;
    int j = threadIdx.x;
    int e0 = row_ofs[n];
    int e1 = row_ofs[n + 1];
    float acc = 0.f;
    int e = e0;
    for (; e + 4 <= e1; e += 4) {
        int sa = esrc[e + 0];
        int sb = esrc[e + 1];
        int sc = esrc[e + 2];
        int sd = esrc[e + 3];
        float va = z[(size_t)sa * OUT_DIM + j];
        float vb = z[(size_t)sb * OUT_DIM + j];
        float vc = z[(size_t)sc * OUT_DIM + j];
        float vd = z[(size_t)sd * OUT_DIM + j];
        acc += (va + vb) + (vc + vd);
    }
    for (; e < e1; ++e) acc += z[(size_t)esrc[e] * OUT_DIM + j];
    float hv = in_norm[n] * acc + b2[j];
    h[(size_t)n * OUT_DIM + j] = (hv > 0.f) ? hv : NEG_SLOPE * hv;
}

// ---------------- per-graph readout (graph_ids sorted) ----------------
__global__ __launch_bounds__(128) void readout_kernel(const float* __restrict__ h,
                                                      const int* __restrict__ gids,
                                                      float* __restrict__ g) {
    int j    = threadIdx.x;
    int n0   = blockIdx.x * RCHUNK;
    int nend = n0 + RCHUNK;
    if (nend > N_NODES) nend = N_NODES;
    float acc = 0.f;
    int   cur = gids[n0];
    for (int n = n0; n < nend; ++n) {
        int gid = gids[n];
        if (gid != cur) {
            atomicAdd(&g[cur * OUT_DIM + j], acc);
            acc = 0.f;
            cur = gid;
        }
        acc += h[(size_t)n * OUT_DIM + j];
    }
    atomicAdd(&g[cur * OUT_DIM + j], acc);
}

// ---------------- classifier: out = g @ w_cls + b_cls ----------------
__global__ __launch_bounds__(256) void cls_kernel(const float* __restrict__ g,
                                                  const float* __restrict__ w_cls,
                                                  const float* __restrict__ b_cls,
                                                  float* __restrict__ out) {
    int t  = threadIdx.x;
    int gr = t >> 1;
    int c  = t & 1;
    float s = b_cls[c];
    for (int k = 0; k < OUT_DIM; ++k) s = fmaf(g[gr * OUT_DIM + k], w_cls[k * 2 + c], s);
    out[t] = s;
}

extern "C" void kernel_launch(void* const* d_in, const int* in_sizes, int n_in,
                              void* d_out, int out_size, void* d_ws, size_t ws_size,
                              hipStream_t stream) {
    const float* feat  = (const float*)d_in[0];
    const int*   src   = (const int*)d_in[1];
    const int*   dst   = (const int*)d_in[2];
    const int*   gids  = (const int*)d_in[3];
    const float* w_red = (const float*)d_in[4];
    const float* b_red = (const float*)d_in[5];
    const float* w_gcn = (const float*)d_in[6];
    const float* b_gcn = (const float*)d_in[7];
    const float* w_cls = (const float*)d_in[8];
    const float* b_cls = (const float*)d_in[9];
    float* out = (float*)d_out;

    // workspace layout
    float* z        = (float*)d_ws;                       // 6.4M floats
    float* h        = z + (size_t)N_NODES * OUT_DIM;      // 6.4M floats
    float* out_norm = h + (size_t)N_NODES * OUT_DIM;      // 50000
    float* in_norm  = out_norm + N_NODES;                 // 50000
    int*   deg_out  = (int*)(in_norm + N_NODES);          // 50000
    int*   deg_in   = deg_out + N_NODES;                  // 50000
    int*   row_ofs  = deg_in + N_NODES;                   // 50001
    int*   cursor   = row_ofs + N_NODES + 1;              // 50000
    int*   esrc     = cursor + N_NODES;                   // 800000
    int*   bsum     = esrc + N_EDGES;                     // NB_SCAN
    int*   bofs     = bsum + NB_SCAN;                     // NB_SCAN
    float* Wc       = (float*)(bofs + NB_SCAN);           // 32768
    float* bc       = Wc + IN_DIM * OUT_DIM;              // 128
    float* g        = bc + OUT_DIM;                       // 16384

    const float* w2 = w_gcn + 2 * OUT_DIM * OUT_DIM;      // layer 2 weights
    const float* b2 = b_gcn + 2 * OUT_DIM;                // layer 2 bias

    hipMemsetAsync(deg_out, 0, 2 * (size_t)N_NODES * sizeof(int), stream);
    hipMemsetAsync(g, 0, (size_t)N_GRAPHS * OUT_DIM * sizeof(float), stream);

    deg_kernel<<<(N_EDGES + 255) / 256, 256, 0, stream>>>(src, dst, deg_out, deg_in);
    norm_kernel<<<(N_NODES + 255) / 256, 256, 0, stream>>>(deg_out, deg_in, out_norm, in_norm);
    partial_kernel<<<NB_SCAN, 256, 0, stream>>>(deg_in, bsum);
    scan_bsums<<<1, 256, 0, stream>>>(bsum, bofs, row_ofs);
    fill_kernel<<<NB_SCAN, 256, 0, stream>>>(deg_in, bofs, row_ofs, cursor);
    build_kernel<<<(N_EDGES + 255) / 256, 256, 0, stream>>>(src, dst, cursor, esrc);
    wc_kernel<<<IN_DIM + 1, OUT_DIM, 0, stream>>>(w_red, b_red, w2, Wc, bc);
    gemm_z<<<(N_NODES + BM - 1) / BM, 256, 0, stream>>>(feat, Wc, bc, out_norm, z);
    gather_kernel<<<N_NODES, 128, 0, stream>>>(z, esrc, row_ofs, in_norm, b2, h);
    readout_kernel<<<(N_NODES + RCHUNK - 1) / RCHUNK, 128, 0, stream>>>(h, gids, g);
    cls_kernel<<<1, 256, 0, stream>>>(g, w_cls, b_cls, out);
}

// Round 4
// 278.549 us; speedup vs baseline: 2.9637x; 1.0125x over previous
//
#include <hip/hip_runtime.h>

#define N_NODES 50000
#define N_EDGES 800000
#define N_GRAPHS 128
#define IN_DIM 256
#define OUT_DIM 128
#define NEG_SLOPE 0.01f

#define BM 64
#define BK 32
#define RCHUNK 64
#define NB_SCAN ((N_NODES + 255) / 256)   // 196 blocks for the scan
#define NREP 8                            // histogram replicas (≈ per-XCD)
#define NE4 (N_EDGES / 4)                 // 200000 int4 edge quads

// ---------------- degree histograms, 8-way replicated ----------------
// rep_out/rep_in: [NREP][N_NODES]. blockIdx&7 ≈ XCD id under round-robin
// dispatch; correctness doesn't depend on the mapping, only locality does.
__global__ __launch_bounds__(256) void deg_kernel(const int4* __restrict__ src4,
                                                  const int4* __restrict__ dst4,
                                                  int* __restrict__ rep_out,
                                                  int* __restrict__ rep_in) {
    int t = blockIdx.x * 256 + threadIdx.x;
    int* ro = rep_out + (size_t)(blockIdx.x & (NREP - 1)) * N_NODES;
    int* ri = rep_in  + (size_t)(blockIdx.x & (NREP - 1)) * N_NODES;
    if (t < NE4) {
        int4 s = src4[t];
        int4 d = dst4[t];
        atomicAdd(&ro[s.x], 1); atomicAdd(&ro[s.y], 1);
        atomicAdd(&ro[s.z], 1); atomicAdd(&ro[s.w], 1);
        atomicAdd(&ri[d.x], 1); atomicAdd(&ri[d.y], 1);
        atomicAdd(&ri[d.z], 1); atomicAdd(&ri[d.w], 1);
    }
}

// ---------------- reduce replicas -> norms + compact deg_in ----------------
__global__ __launch_bounds__(256) void norm_kernel(const int* __restrict__ rep_out,
                                                   const int* __restrict__ rep_in,
                                                   float* __restrict__ out_norm,
                                                   float* __restrict__ in_norm,
                                                   int* __restrict__ deg_in_tot) {
    int i = blockIdx.x * 256 + threadIdx.x;
    if (i < N_NODES) {
        int so = 0, si = 0;
#pragma unroll
        for (int r = 0; r < NREP; ++r) {
            so += rep_out[(size_t)r * N_NODES + i];
            si += rep_in[(size_t)r * N_NODES + i];
        }
        deg_in_tot[i] = si;
        int dq = so > 1 ? so : 1;
        int di = si > 1 ? si : 1;
        out_norm[i] = rsqrtf((float)dq);
        in_norm[i]  = rsqrtf((float)di);
    }
}

// ---------------- multi-block scan phase 1: per-block sums ----------------
__global__ __launch_bounds__(256) void partial_kernel(const int* __restrict__ deg_in,
                                                      int* __restrict__ bsum) {
    __shared__ int red[256];
    int t   = threadIdx.x;
    int idx = blockIdx.x * 256 + t;
    red[t] = (idx < N_NODES) ? deg_in[idx] : 0;
    __syncthreads();
    for (int off = 128; off > 0; off >>= 1) {
        if (t < off) red[t] += red[t + off];
        __syncthreads();
    }
    if (t == 0) bsum[blockIdx.x] = red[0];
}

// ---------------- phase 2: scan the 196 block sums (one block) ----------------
__global__ __launch_bounds__(256) void scan_bsums(const int* __restrict__ bsum,
                                                  int* __restrict__ bofs,
                                                  int* __restrict__ row_ofs) {
    __shared__ int sh[256];
    int t = threadIdx.x;
    int v = (t < NB_SCAN) ? bsum[t] : 0;
    sh[t] = v;
    __syncthreads();
    for (int off = 1; off < 256; off <<= 1) {
        int a = sh[t];
        int b = (t >= off) ? sh[t - off] : 0;
        __syncthreads();
        sh[t] = a + b;
        __syncthreads();
    }
    if (t < NB_SCAN) bofs[t] = sh[t] - v;                    // exclusive
    if (t == 255)    row_ofs[N_NODES] = sh[NB_SCAN - 1];     // total (= N_EDGES)
}

// ---------------- phase 3: block-local scan + offset -> row_ofs, cursor ----------------
__global__ __launch_bounds__(256) void fill_kernel(const int* __restrict__ deg_in,
                                                   const int* __restrict__ bofs,
                                                   int* __restrict__ row_ofs,
                                                   int* __restrict__ cursor) {
    __shared__ int sh[256];
    int t   = threadIdx.x;
    int idx = blockIdx.x * 256 + t;
    int v   = (idx < N_NODES) ? deg_in[idx] : 0;
    sh[t] = v;
    __syncthreads();
    for (int off = 1; off < 256; off <<= 1) {
        int a = sh[t];
        int b = (t >= off) ? sh[t - off] : 0;
        __syncthreads();
        sh[t] = a + b;
        __syncthreads();
    }
    if (idx < N_NODES) {
        int r = bofs[blockIdx.x] + sh[t] - v;   // global exclusive prefix
        row_ofs[idx] = r;
        cursor[idx]  = r;
    }
}

// ---------------- bucket fill: esrc grouped by dst ----------------
__global__ __launch_bounds__(256) void build_kernel(const int4* __restrict__ src4,
                                                    const int4* __restrict__ dst4,
                                                    int* __restrict__ cursor,
                                                    int* __restrict__ esrc) {
    int t = blockIdx.x * 256 + threadIdx.x;
    if (t < NE4) {
        int4 s = src4[t];
        int4 d = dst4[t];
        esrc[atomicAdd(&cursor[d.x], 1)] = s.x;
        esrc[atomicAdd(&cursor[d.y], 1)] = s.y;
        esrc[atomicAdd(&cursor[d.z], 1)] = s.z;
        esrc[atomicAdd(&cursor[d.w], 1)] = s.w;
    }
}

// ---------------- fold Wc = w_red @ w2, bc = b_red @ w2 ----------------
__global__ __launch_bounds__(128) void wc_kernel(const float* __restrict__ w_red,
                                                 const float* __restrict__ b_red,
                                                 const float* __restrict__ w2,
                                                 float* __restrict__ Wc,
                                                 float* __restrict__ bc) {
    int j = threadIdx.x;   // 0..127
    int i = blockIdx.x;    // 0..256 (block 256 computes bc)
    const float* vin = (i < IN_DIM) ? (w_red + (size_t)i * OUT_DIM) : b_red;
    float s = 0.f;
    for (int k = 0; k < OUT_DIM; ++k) s = fmaf(vin[k], w2[k * OUT_DIM + j], s);
    if (i < IN_DIM) Wc[i * OUT_DIM + j] = s;
    else            bc[j] = s;
}

// ---------------- z = out_norm * (feat @ Wc + bc) ----------------
__global__ __launch_bounds__(256) void gemm_z(const float* __restrict__ feat,
                                              const float* __restrict__ Wc,
                                              const float* __restrict__ bc,
                                              const float* __restrict__ out_norm,
                                              float* __restrict__ z) {
    __shared__ float As[BM][BK + 4];
    __shared__ float Bs[BK][OUT_DIM];

    int t  = threadIdx.x;
    int bm = blockIdx.x * BM;
    int cg = t & 15;
    int rg = t >> 4;

    float acc[4][8];
#pragma unroll
    for (int i = 0; i < 4; ++i)
#pragma unroll
        for (int j = 0; j < 8; ++j) acc[i][j] = 0.f;

    for (int k0 = 0; k0 < IN_DIM; k0 += BK) {
        int ar = t >> 3;
        int ak = (t & 7) * 4;
#pragma unroll
        for (int h = 0; h < 2; ++h) {
            int row = ar + h * 32;
            int gm  = bm + row;
            float4 v = make_float4(0.f, 0.f, 0.f, 0.f);
            if (gm < N_NODES) v = *(const float4*)&feat[(size_t)gm * IN_DIM + k0 + ak];
            *(float4*)&As[row][ak] = v;
        }
        int bn  = (t & 31) * 4;
        int bk0 = t >> 5;
#pragma unroll
        for (int i = 0; i < 4; ++i) {
            int k = bk0 + i * 8;
            *(float4*)&Bs[k][bn] = *(const float4*)&Wc[(size_t)(k0 + k) * OUT_DIM + bn];
        }
        __syncthreads();

#pragma unroll
        for (int k = 0; k < BK; ++k) {
            float a[4];
#pragma unroll
            for (int i = 0; i < 4; ++i) a[i] = As[rg * 4 + i][k];
            float4 b0 = *(const float4*)&Bs[k][cg * 8];
            float4 b1 = *(const float4*)&Bs[k][cg * 8 + 4];
            float b[8] = {b0.x, b0.y, b0.z, b0.w, b1.x, b1.y, b1.z, b1.w};
#pragma unroll
            for (int i = 0; i < 4; ++i)
#pragma unroll
                for (int j = 0; j < 8; ++j)
                    acc[i][j] = fmaf(a[i], b[j], acc[i][j]);
        }
        __syncthreads();
    }

#pragma unroll
    for (int i = 0; i < 4; ++i) {
        int gm = bm + rg * 4 + i;
        if (gm < N_NODES) {
            float on = out_norm[gm];
            float4 o0, o1;
            o0.x = on * (acc[i][0] + bc[cg * 8 + 0]);
            o0.y = on * (acc[i][1] + bc[cg * 8 + 1]);
            o0.z = on * (acc[i][2] + bc[cg * 8 + 2]);
            o0.w = on * (acc[i][3] + bc[cg * 8 + 3]);
            o1.x = on * (acc[i][4] + bc[cg * 8 + 4]);
            o1.y = on * (acc[i][5] + bc[cg * 8 + 5]);
            o1.z = on * (acc[i][6] + bc[cg * 8 + 6]);
            o1.w = on * (acc[i][7] + bc[cg * 8 + 7]);
            *(float4*)&z[(size_t)gm * OUT_DIM + cg * 8]     = o0;
            *(float4*)&z[(size_t)gm * OUT_DIM + cg * 8 + 4] = o1;
        }
    }
}

// ---------------- pull-model aggregate + fused in_norm/bias/leaky_relu ----------------
__global__ __launch_bounds__(128) void gather_kernel(const float* __restrict__ z,
                                                     const int* __restrict__ esrc,
                                                     const int* __restrict__ row_ofs,
                                                     const float* __restrict__ in_norm,
                                                     const float* __restrict__ b2,
                                                     float* __restrict__ h) {
    int n = blockIdx.x;
    int j = threadIdx.x;
    int e0 = row_ofs[n];
    int e1 = row_ofs[n + 1];
    float acc = 0.f;
    int e = e0;
    for (; e + 4 <= e1; e += 4) {
        int sa = esrc[e + 0];
        int sb = esrc[e + 1];
        int sc = esrc[e + 2];
        int sd = esrc[e + 3];
        float va = z[(size_t)sa * OUT_DIM + j];
        float vb = z[(size_t)sb * OUT_DIM + j];
        float vc = z[(size_t)sc * OUT_DIM + j];
        float vd = z[(size_t)sd * OUT_DIM + j];
        acc += (va + vb) + (vc + vd);
    }
    for (; e < e1; ++e) acc += z[(size_t)esrc[e] * OUT_DIM + j];
    float hv = in_norm[n] * acc + b2[j];
    h[(size_t)n * OUT_DIM + j] = (hv > 0.f) ? hv : NEG_SLOPE * hv;
}

// ---------------- per-graph readout (graph_ids sorted) ----------------
__global__ __launch_bounds__(128) void readout_kernel(const float* __restrict__ h,
                                                      const int* __restrict__ gids,
                                                      float* __restrict__ g) {
    int j    = threadIdx.x;
    int n0   = blockIdx.x * RCHUNK;
    int nend = n0 + RCHUNK;
    if (nend > N_NODES) nend = N_NODES;
    float acc = 0.f;
    int   cur = gids[n0];
    for (int n = n0; n < nend; ++n) {
        int gid = gids[n];
        if (gid != cur) {
            atomicAdd(&g[cur * OUT_DIM + j], acc);
            acc = 0.f;
            cur = gid;
        }
        acc += h[(size_t)n * OUT_DIM + j];
    }
    atomicAdd(&g[cur * OUT_DIM + j], acc);
}

// ---------------- classifier: out = g @ w_cls + b_cls ----------------
__global__ __launch_bounds__(256) void cls_kernel(const float* __restrict__ g,
                                                  const float* __restrict__ w_cls,
                                                  const float* __restrict__ b_cls,
                                                  float* __restrict__ out) {
    int t  = threadIdx.x;
    int gr = t >> 1;
    int c  = t & 1;
    float s = b_cls[c];
    for (int k = 0; k < OUT_DIM; ++k) s = fmaf(g[gr * OUT_DIM + k], w_cls[k * 2 + c], s);
    out[t] = s;
}

extern "C" void kernel_launch(void* const* d_in, const int* in_sizes, int n_in,
                              void* d_out, int out_size, void* d_ws, size_t ws_size,
                              hipStream_t stream) {
    const float* feat  = (const float*)d_in[0];
    const int*   src   = (const int*)d_in[1];
    const int*   dst   = (const int*)d_in[2];
    const int*   gids  = (const int*)d_in[3];
    const float* w_red = (const float*)d_in[4];
    const float* b_red = (const float*)d_in[5];
    const float* w_gcn = (const float*)d_in[6];
    const float* b_gcn = (const float*)d_in[7];
    const float* w_cls = (const float*)d_in[8];
    const float* b_cls = (const float*)d_in[9];
    float* out = (float*)d_out;

    // workspace layout
    float* z        = (float*)d_ws;                       // 6.4M floats
    float* h        = z + (size_t)N_NODES * OUT_DIM;      // 6.4M floats
    float* out_norm = h + (size_t)N_NODES * OUT_DIM;      // 50000
    float* in_norm  = out_norm + N_NODES;                 // 50000
    int*   deg_in   = (int*)(in_norm + N_NODES);          // 50000 (compact)
    int*   row_ofs  = deg_in + N_NODES;                   // 50001
    int*   cursor   = row_ofs + N_NODES + 1;              // 50000
    int*   esrc     = cursor + N_NODES;                   // 800000
    int*   bsum     = esrc + N_EDGES;                     // NB_SCAN
    int*   bofs     = bsum + NB_SCAN;                     // NB_SCAN
    float* Wc       = (float*)(bofs + NB_SCAN);           // 32768
    float* bc       = Wc + IN_DIM * OUT_DIM;              // 128
    float* g        = bc + OUT_DIM;                       // 16384

    // replicated degree histograms ALIAS the z buffer (deg phase finishes
    // before gemm_z writes z; single stream => safe and deterministic).
    int* rep_out = (int*)z;                               // [NREP][N_NODES]
    int* rep_in  = rep_out + (size_t)NREP * N_NODES;      // [NREP][N_NODES]

    const float* w2 = w_gcn + 2 * OUT_DIM * OUT_DIM;      // layer 2 weights
    const float* b2 = b_gcn + 2 * OUT_DIM;                // layer 2 bias

    hipMemsetAsync(rep_out, 0, 2 * (size_t)NREP * N_NODES * sizeof(int), stream);
    hipMemsetAsync(g, 0, (size_t)N_GRAPHS * OUT_DIM * sizeof(float), stream);

    deg_kernel<<<(NE4 + 255) / 256, 256, 0, stream>>>((const int4*)src, (const int4*)dst,
                                                      rep_out, rep_in);
    norm_kernel<<<(N_NODES + 255) / 256, 256, 0, stream>>>(rep_out, rep_in,
                                                           out_norm, in_norm, deg_in);
    partial_kernel<<<NB_SCAN, 256, 0, stream>>>(deg_in, bsum);
    scan_bsums<<<1, 256, 0, stream>>>(bsum, bofs, row_ofs);
    fill_kernel<<<NB_SCAN, 256, 0, stream>>>(deg_in, bofs, row_ofs, cursor);
    build_kernel<<<(NE4 + 255) / 256, 256, 0, stream>>>((const int4*)src, (const int4*)dst,
                                                        cursor, esrc);
    wc_kernel<<<IN_DIM + 1, OUT_DIM, 0, stream>>>(w_red, b_red, w2, Wc, bc);
    gemm_z<<<(N_NODES + BM - 1) / BM, 256, 0, stream>>>(feat, Wc, bc, out_norm, z);
    gather_kernel<<<N_NODES, 128, 0, stream>>>(z, esrc, row_ofs, in_norm, b2, h);
    readout_kernel<<<(N_NODES + RCHUNK - 1) / RCHUNK, 128, 0, stream>>>(h, gids, g);
    cls_kernel<<<1, 256, 0, stream>>>(g, w_cls, b_cls, out);
}

// Round 5
// 235.376 us; speedup vs baseline: 3.5073x; 1.1834x over previous
//
#include <hip/hip_runtime.h>

#define N_NODES 50000
#define N_EDGES 800000
#define N_GRAPHS 128
#define IN_DIM 256
#define OUT_DIM 128
#define NEG_SLOPE 0.01f

#define BM 64
#define BK 32
#define RCHUNK 64
#define NB_SCAN ((N_NODES + 255) / 256)   // 196 blocks for the scan

#define NSLICE 4
#define SLICE 12544                        // 4*12544 = 50176 >= N_NODES
#define NTOT (NSLICE * SLICE)              // 50176
#define NCHUNK 32
#define NE4 (N_EDGES / 4)                  // 200000 int4 quads
#define QPC (NE4 / NCHUNK)                 // 6250 quads per chunk

// ---------------- degree histograms: LDS slices, zero global atomics ----------------
// grid = 2 hists x 4 slices x 32 chunks = 256 blocks.
// Each block LDS-accumulates its (hist, node-slice) over its edge chunk, then
// flushes with plain int4 stores into rep[hist][chunk][node]. norm_kernel reduces.
__global__ __launch_bounds__(256) void deg_kernel(const int4* __restrict__ src4,
                                                  const int4* __restrict__ dst4,
                                                  int* __restrict__ rep) {
    __shared__ int bins[SLICE];
    int b     = blockIdx.x;
    int hist  = b >> 7;          // 0: src (out-deg), 1: dst (in-deg)
    int rem   = b & 127;
    int slice = rem >> 5;
    int chunk = rem & 31;
    const int4* ea = hist ? dst4 : src4;
    int lo = slice * SLICE;

    for (int i = threadIdx.x; i < SLICE; i += 256) bins[i] = 0;
    __syncthreads();

    int q0 = chunk * QPC;
    int q1 = q0 + QPC;
    for (int q = q0 + threadIdx.x; q < q1; q += 256) {
        int4 e = ea[q];
        unsigned a0 = (unsigned)(e.x - lo); if (a0 < SLICE) atomicAdd(&bins[a0], 1);
        unsigned a1 = (unsigned)(e.y - lo); if (a1 < SLICE) atomicAdd(&bins[a1], 1);
        unsigned a2 = (unsigned)(e.z - lo); if (a2 < SLICE) atomicAdd(&bins[a2], 1);
        unsigned a3 = (unsigned)(e.w - lo); if (a3 < SLICE) atomicAdd(&bins[a3], 1);
    }
    __syncthreads();

    int* rp = rep + (size_t)(hist * NCHUNK + chunk) * NTOT + lo;
    for (int i = threadIdx.x; i < SLICE / 4; i += 256)
        *(int4*)&rp[i * 4] = *(const int4*)&bins[i * 4];
}

// ---------------- reduce replicas -> norms + compact deg_in ----------------
__global__ __launch_bounds__(256) void norm_kernel(const int* __restrict__ rep,
                                                   float* __restrict__ out_norm,
                                                   float* __restrict__ in_norm,
                                                   int* __restrict__ deg_in_tot) {
    int i = blockIdx.x * 256 + threadIdx.x;
    if (i < N_NODES) {
        int so = 0, si = 0;
#pragma unroll
        for (int c = 0; c < NCHUNK; ++c) {
            so += rep[(size_t)c * NTOT + i];
            si += rep[(size_t)(NCHUNK + c) * NTOT + i];
        }
        deg_in_tot[i] = si;
        int dq = so > 1 ? so : 1;
        int di = si > 1 ? si : 1;
        out_norm[i] = rsqrtf((float)dq);
        in_norm[i]  = rsqrtf((float)di);
    }
}

// ---------------- multi-block scan phase 1: per-block sums ----------------
__global__ __launch_bounds__(256) void partial_kernel(const int* __restrict__ deg_in,
                                                      int* __restrict__ bsum) {
    __shared__ int red[256];
    int t   = threadIdx.x;
    int idx = blockIdx.x * 256 + t;
    red[t] = (idx < N_NODES) ? deg_in[idx] : 0;
    __syncthreads();
    for (int off = 128; off > 0; off >>= 1) {
        if (t < off) red[t] += red[t + off];
        __syncthreads();
    }
    if (t == 0) bsum[blockIdx.x] = red[0];
}

// ---------------- phase 2: scan the 196 block sums (one block) ----------------
__global__ __launch_bounds__(256) void scan_bsums(const int* __restrict__ bsum,
                                                  int* __restrict__ bofs,
                                                  int* __restrict__ row_ofs) {
    __shared__ int sh[256];
    int t = threadIdx.x;
    int v = (t < NB_SCAN) ? bsum[t] : 0;
    sh[t] = v;
    __syncthreads();
    for (int off = 1; off < 256; off <<= 1) {
        int a = sh[t];
        int b = (t >= off) ? sh[t - off] : 0;
        __syncthreads();
        sh[t] = a + b;
        __syncthreads();
    }
    if (t < NB_SCAN) bofs[t] = sh[t] - v;                    // exclusive
    if (t == 255)    row_ofs[N_NODES] = sh[NB_SCAN - 1];     // total (= N_EDGES)
}

// ---------------- phase 3: block-local scan + offset -> row_ofs, cursor ----------------
__global__ __launch_bounds__(256) void fill_kernel(const int* __restrict__ deg_in,
                                                   const int* __restrict__ bofs,
                                                   int* __restrict__ row_ofs,
                                                   int* __restrict__ cursor) {
    __shared__ int sh[256];
    int t   = threadIdx.x;
    int idx = blockIdx.x * 256 + t;
    int v   = (idx < N_NODES) ? deg_in[idx] : 0;
    sh[t] = v;
    __syncthreads();
    for (int off = 1; off < 256; off <<= 1) {
        int a = sh[t];
        int b = (t >= off) ? sh[t - off] : 0;
        __syncthreads();
        sh[t] = a + b;
        __syncthreads();
    }
    if (idx < N_NODES) {
        int r = bofs[blockIdx.x] + sh[t] - v;   // global exclusive prefix
        row_ofs[idx] = r;
        cursor[idx]  = r;
    }
}

// ---------------- bucket fill: esrc grouped by dst ----------------
__global__ __launch_bounds__(256) void build_kernel(const int4* __restrict__ src4,
                                                    const int4* __restrict__ dst4,
                                                    int* __restrict__ cursor,
                                                    int* __restrict__ esrc) {
    int t = blockIdx.x * 256 + threadIdx.x;
    if (t < NE4) {
        int4 s = src4[t];
        int4 d = dst4[t];
        esrc[atomicAdd(&cursor[d.x], 1)] = s.x;
        esrc[atomicAdd(&cursor[d.y], 1)] = s.y;
        esrc[atomicAdd(&cursor[d.z], 1)] = s.z;
        esrc[atomicAdd(&cursor[d.w], 1)] = s.w;
    }
}

// ---------------- fold Wc = w_red @ w2, bc = b_red @ w2 ----------------
__global__ __launch_bounds__(128) void wc_kernel(const float* __restrict__ w_red,
                                                 const float* __restrict__ b_red,
                                                 const float* __restrict__ w2,
                                                 float* __restrict__ Wc,
                                                 float* __restrict__ bc) {
    int j = threadIdx.x;   // 0..127
    int i = blockIdx.x;    // 0..256 (block 256 computes bc)
    const float* vin = (i < IN_DIM) ? (w_red + (size_t)i * OUT_DIM) : b_red;
    float s = 0.f;
    for (int k = 0; k < OUT_DIM; ++k) s = fmaf(vin[k], w2[k * OUT_DIM + j], s);
    if (i < IN_DIM) Wc[i * OUT_DIM + j] = s;
    else            bc[j] = s;
}

// ---------------- z = out_norm * (feat @ Wc + bc) ----------------
// A-tile stored TRANSPOSED (Ast[k][row]) so inner-loop A-read is one
// conflict-free ds_read_b128; old row-major As had 4-8 way write conflicts.
__global__ __launch_bounds__(256) void gemm_z(const float* __restrict__ feat,
                                              const float* __restrict__ Wc,
                                              const float* __restrict__ bc,
                                              const float* __restrict__ out_norm,
                                              float* __restrict__ z) {
    __shared__ float Ast[BK][BM + 4];    // [k][row], pad keeps b128 banks disjoint
    __shared__ float Bs[BK][OUT_DIM];

    int t  = threadIdx.x;
    int bm = blockIdx.x * BM;
    int cg = t & 15;
    int rg = t >> 4;

    float acc[4][8];
#pragma unroll
    for (int i = 0; i < 4; ++i)
#pragma unroll
        for (int j = 0; j < 8; ++j) acc[i][j] = 0.f;

    for (int k0 = 0; k0 < IN_DIM; k0 += BK) {
        int ar = t >> 3;
        int ak = (t & 7) * 4;
#pragma unroll
        for (int h = 0; h < 2; ++h) {
            int row = ar + h * 32;
            int gm  = bm + row;
            float4 v = make_float4(0.f, 0.f, 0.f, 0.f);
            if (gm < N_NODES) v = *(const float4*)&feat[(size_t)gm * IN_DIM + k0 + ak];
            Ast[ak + 0][row] = v.x;
            Ast[ak + 1][row] = v.y;
            Ast[ak + 2][row] = v.z;
            Ast[ak + 3][row] = v.w;
        }
        int bn  = (t & 31) * 4;
        int bk0 = t >> 5;
#pragma unroll
        for (int i = 0; i < 4; ++i) {
            int k = bk0 + i * 8;
            *(float4*)&Bs[k][bn] = *(const float4*)&Wc[(size_t)(k0 + k) * OUT_DIM + bn];
        }
        __syncthreads();

#pragma unroll
        for (int k = 0; k < BK; ++k) {
            float4 a4 = *(const float4*)&Ast[k][rg * 4];
            float a[4] = {a4.x, a4.y, a4.z, a4.w};
            float4 b0 = *(const float4*)&Bs[k][cg * 8];
            float4 b1 = *(const float4*)&Bs[k][cg * 8 + 4];
            float b[8] = {b0.x, b0.y, b0.z, b0.w, b1.x, b1.y, b1.z, b1.w};
#pragma unroll
            for (int i = 0; i < 4; ++i)
#pragma unroll
                for (int j = 0; j < 8; ++j)
                    acc[i][j] = fmaf(a[i], b[j], acc[i][j]);
        }
        __syncthreads();
    }

#pragma unroll
    for (int i = 0; i < 4; ++i) {
        int gm = bm + rg * 4 + i;
        if (gm < N_NODES) {
            float on = out_norm[gm];
            float4 o0, o1;
            o0.x = on * (acc[i][0] + bc[cg * 8 + 0]);
            o0.y = on * (acc[i][1] + bc[cg * 8 + 1]);
            o0.z = on * (acc[i][2] + bc[cg * 8 + 2]);
            o0.w = on * (acc[i][3] + bc[cg * 8 + 3]);
            o1.x = on * (acc[i][4] + bc[cg * 8 + 4]);
            o1.y = on * (acc[i][5] + bc[cg * 8 + 5]);
            o1.z = on * (acc[i][6] + bc[cg * 8 + 6]);
            o1.w = on * (acc[i][7] + bc[cg * 8 + 7]);
            *(float4*)&z[(size_t)gm * OUT_DIM + cg * 8]     = o0;
            *(float4*)&z[(size_t)gm * OUT_DIM + cg * 8 + 4] = o1;
        }
    }
}

// ---------------- pull-model aggregate + fused in_norm/bias/leaky_relu ----------------
__global__ __launch_bounds__(128) void gather_kernel(const float* __restrict__ z,
                                                     const int* __restrict__ esrc,
                                                     const int* __restrict__ row_ofs,
                                                     const float* __restrict__ in_norm,
                                                     const float* __restrict__ b2,
                                                     float* __restrict__ h) {
    int n = blockIdx.x;
    int j = threadIdx.x;
    int e0 = row_ofs[n];
    int e1 = row_ofs[n + 1];
    float acc = 0.f;
    int e = e0;
    for (; e + 4 <= e1; e += 4) {
        int sa = esrc[e + 0];
        int sb = esrc[e + 1];
        int sc = esrc[e + 2];
        int sd = esrc[e + 3];
        float va = z[(size_t)sa * OUT_DIM + j];
        float vb = z[(size_t)sb * OUT_DIM + j];
        float vc = z[(size_t)sc * OUT_DIM + j];
        float vd = z[(size_t)sd * OUT_DIM + j];
        acc += (va + vb) + (vc + vd);
    }
    for (; e < e1; ++e) acc += z[(size_t)esrc[e] * OUT_DIM + j];
    float hv = in_norm[n] * acc + b2[j];
    h[(size_t)n * OUT_DIM + j] = (hv > 0.f) ? hv : NEG_SLOPE * hv;
}

// ---------------- per-graph readout (graph_ids sorted) ----------------
__global__ __launch_bounds__(128) void readout_kernel(const float* __restrict__ h,
                                                      const int* __restrict__ gids,
                                                      float* __restrict__ g) {
    int j    = threadIdx.x;
    int n0   = blockIdx.x * RCHUNK;
    int nend = n0 + RCHUNK;
    if (nend > N_NODES) nend = N_NODES;
    float acc = 0.f;
    int   cur = gids[n0];
    for (int n = n0; n < nend; ++n) {
        int gid = gids[n];
        if (gid != cur) {
            atomicAdd(&g[cur * OUT_DIM + j], acc);
            acc = 0.f;
            cur = gid;
        }
        acc += h[(size_t)n * OUT_DIM + j];
    }
    atomicAdd(&g[cur * OUT_DIM + j], acc);
}

// ---------------- classifier: out = g @ w_cls + b_cls ----------------
__global__ __launch_bounds__(256) void cls_kernel(const float* __restrict__ g,
                                                  const float* __restrict__ w_cls,
                                                  const float* __restrict__ b_cls,
                                                  float* __restrict__ out) {
    int t  = threadIdx.x;
    int gr = t >> 1;
    int c  = t & 1;
    float s = b_cls[c];
    for (int k = 0; k < OUT_DIM; ++k) s = fmaf(g[gr * OUT_DIM + k], w_cls[k * 2 + c], s);
    out[t] = s;
}

extern "C" void kernel_launch(void* const* d_in, const int* in_sizes, int n_in,
                              void* d_out, int out_size, void* d_ws, size_t ws_size,
                              hipStream_t stream) {
    const float* feat  = (const float*)d_in[0];
    const int*   src   = (const int*)d_in[1];
    const int*   dst   = (const int*)d_in[2];
    const int*   gids  = (const int*)d_in[3];
    const float* w_red = (const float*)d_in[4];
    const float* b_red = (const float*)d_in[5];
    const float* w_gcn = (const float*)d_in[6];
    const float* b_gcn = (const float*)d_in[7];
    const float* w_cls = (const float*)d_in[8];
    const float* b_cls = (const float*)d_in[9];
    float* out = (float*)d_out;

    // workspace layout
    float* z        = (float*)d_ws;                       // 6.4M floats (25.6MB)
    float* h        = z + (size_t)N_NODES * OUT_DIM;      // 6.4M floats
    float* out_norm = h + (size_t)N_NODES * OUT_DIM;      // 50000
    float* in_norm  = out_norm + N_NODES;                 // 50000
    int*   deg_in   = (int*)(in_norm + N_NODES);          // 50000 (compact)
    int*   row_ofs  = deg_in + N_NODES;                   // 50001
    int*   cursor   = row_ofs + N_NODES + 1;              // 50000
    int*   esrc     = cursor + N_NODES;                   // 800000
    int*   bsum     = esrc + N_EDGES;                     // NB_SCAN
    int*   bofs     = bsum + NB_SCAN;                     // NB_SCAN
    float* Wc       = (float*)(bofs + NB_SCAN);           // 32768
    float* bc       = Wc + IN_DIM * OUT_DIM;              // 128
    float* g        = bc + OUT_DIM;                       // 16384

    // per-chunk histogram replicas ALIAS the z buffer: rep[2][NCHUNK][NTOT]
    // (12.85MB <= 25.6MB; deg phase completes before gemm_z writes z).
    int* rep = (int*)z;

    const float* w2 = w_gcn + 2 * OUT_DIM * OUT_DIM;      // layer 2 weights
    const float* b2 = b_gcn + 2 * OUT_DIM;                // layer 2 bias

    hipMemsetAsync(g, 0, (size_t)N_GRAPHS * OUT_DIM * sizeof(float), stream);

    deg_kernel<<<2 * NSLICE * NCHUNK, 256, 0, stream>>>((const int4*)src, (const int4*)dst, rep);
    norm_kernel<<<(N_NODES + 255) / 256, 256, 0, stream>>>(rep, out_norm, in_norm, deg_in);
    partial_kernel<<<NB_SCAN, 256, 0, stream>>>(deg_in, bsum);
    scan_bsums<<<1, 256, 0, stream>>>(bsum, bofs, row_ofs);
    fill_kernel<<<NB_SCAN, 256, 0, stream>>>(deg_in, bofs, row_ofs, cursor);
    build_kernel<<<(NE4 + 255) / 256, 256, 0, stream>>>((const int4*)src, (const int4*)dst,
                                                        cursor, esrc);
    wc_kernel<<<IN_DIM + 1, OUT_DIM, 0, stream>>>(w_red, b_red, w2, Wc, bc);
    gemm_z<<<(N_NODES + BM - 1) / BM, 256, 0, stream>>>(feat, Wc, bc, out_norm, z);
    gather_kernel<<<N_NODES, 128, 0, stream>>>(z, esrc, row_ofs, in_norm, b2, h);
    readout_kernel<<<(N_NODES + RCHUNK - 1) / RCHUNK, 128, 0, stream>>>(h, gids, g);
    cls_kernel<<<1, 256, 0, stream>>>(g, w_cls, b_cls, out);
}